// Round 1
// baseline (147.106 us; speedup 1.0000x reference)
//
#include <hip/hip_runtime.h>
#include <math.h>

#define TAU_F 0.07f
#define B_ 2
#define CIN 64
#define H_ 128
#define W_ 256
#define CC 96      // COST_CH
#define G_ 8
#define CG 12
#define DP 32
#define HW_ (H_*W_)
#define ROWF (W_*CG)   // floats per (b,h,g) row in plane layout = 3072

// ---------------------------------------------------------------------------
// Kernel 1: transpose weights [96][64] -> [64][96] so the projection kernel's
// inner loop reads 96 contiguous floats per input channel (scalar s_load path).
// ---------------------------------------------------------------------------
__global__ void wtrans_kernel(const float* __restrict__ WL,
                              const float* __restrict__ WR,
                              float* __restrict__ WtL,
                              float* __restrict__ WtR) {
    int i = blockIdx.x * 256 + threadIdx.x;       // 0 .. 2*6144-1
    if (i >= 2 * CIN * CC) return;
    int side = i / (CIN * CC);
    int r = i % (CIN * CC);
    int c = r / CC;
    int o = r % CC;
    const float* src = side ? WR : WL;
    float* dst = side ? WtR : WtL;
    dst[r] = src[o * CIN + c];                    // Wt[c][o] = W[o][c]
}

// ---------------------------------------------------------------------------
// Kernel 2: projection + L2 norm.
// One thread = one pixel (b,h,w). y[96] accumulators in VGPRs; weights read
// uniformly (scalar loads). Output in "plane" layout per (b,h,g) row:
//   base = ((b*H+h)*G+g)*3072 ; float4 plane j (j=0..2) at j*1024 + w*4
// so channel cg = 4*j+e of pixel w lives at base + j*1024 + w*4 + e.
// ---------------------------------------------------------------------------
__global__ __launch_bounds__(256) void proj_kernel(
    const float* __restrict__ F_L, const float* __restrict__ F_R,
    const float* __restrict__ WtL, const float* __restrict__ WtR,
    float* __restrict__ outL, float* __restrict__ outR)
{
    const int side = blockIdx.y;
    const float* F  = side ? F_R : F_L;
    const float* Wt = side ? WtR : WtL;
    float* out      = side ? outR : outL;

    int p  = blockIdx.x * 256 + threadIdx.x;      // 0..65535
    int b  = p / HW_;
    int hw = p % HW_;
    int h  = hw / W_;
    int w  = hw % W_;

    float y[CC];
#pragma unroll
    for (int o = 0; o < CC; ++o) y[o] = 0.f;

    const float* fp = F + (size_t)b * CIN * HW_ + hw;
    for (int c = 0; c < CIN; ++c) {
        float f = fp[(size_t)c * HW_];            // coalesced across threads
        const float* wr = Wt + c * CC;            // uniform address -> s_load
#pragma unroll
        for (int o = 0; o < CC; ++o) y[o] = fmaf(f, wr[o], y[o]);
    }

    float ss = 0.f;
#pragma unroll
    for (int o = 0; o < CC; ++o) ss = fmaf(y[o], y[o], ss);
    float r = 1.0f / fmaxf(sqrtf(ss), 1e-12f);

    size_t base = (size_t)(b * H_ + h) * (G_ * ROWF);
#pragma unroll
    for (int g = 0; g < G_; ++g) {
#pragma unroll
        for (int j = 0; j < 3; ++j) {
            float4 v;
            v.x = y[g*CG + j*4 + 0] * r;
            v.y = y[g*CG + j*4 + 1] * r;
            v.z = y[g*CG + j*4 + 2] * r;
            v.w = y[g*CG + j*4 + 3] * r;
            // lanes stride 16B -> fully coalesced dwordx4 store
            *(float4*)&out[base + (size_t)g * ROWF + j * (W_*4) + w * 4] = v;
        }
    }
}

// ---------------------------------------------------------------------------
// Kernel 3: shifted group-dot cost volume.
// One block = one (b,g,h) row. Stage FL row + FR row (12 KiB each) in LDS,
// then each thread (= one w) loops d=0..31 reading FR at clip(w-d,0) —
// contiguous 16B/lane ds_read_b128, conflict-free (clamped lanes broadcast).
// ---------------------------------------------------------------------------
__global__ __launch_bounds__(256) void sim_kernel(
    const float* __restrict__ PL, const float* __restrict__ PR,
    float* __restrict__ out)
{
    __shared__ float flS[ROWF];
    __shared__ float frS[ROWF];
    __shared__ float psiS[DP];

    int blk = blockIdx.x;
    int h = blk % H_;
    int g = (blk / H_) % G_;
    int b = blk / (H_ * G_);
    int tid = threadIdx.x;

    size_t base = ((size_t)(b * H_ + h) * G_ + g) * ROWF;

    // linear float4 copy global -> LDS (coalesced, conflict-free)
#pragma unroll
    for (int i = tid; i < ROWF / 4; i += 256) {
        *(float4*)&flS[i * 4] = *(const float4*)&PL[base + (size_t)i * 4];
        *(float4*)&frS[i * 4] = *(const float4*)&PR[base + (size_t)i * 4];
    }
    if (tid < DP)
        psiS[tid] = -sinf(6.28318530717958647692f * (float)tid / (float)DP) / TAU_F;
    __syncthreads();

    const int w = tid;
    float4 fl0 = *(const float4*)&flS[0*1024 + w*4];
    float4 fl1 = *(const float4*)&flS[1*1024 + w*4];
    float4 fl2 = *(const float4*)&flS[2*1024 + w*4];

    const float A = -1.0f / (3.46410161513775459f * TAU_F);  // -1/(sqrt(12)*tau)
    size_t ob = ((size_t)(b * G_ + g) * DP * H_ + h) * W_ + w;

#pragma unroll
    for (int d = 0; d < DP; ++d) {
        int wd = w - d; if (wd < 0) wd = 0;
        float4 a0 = *(const float4*)&frS[0*1024 + wd*4];
        float4 a1 = *(const float4*)&frS[1*1024 + wd*4];
        float4 a2 = *(const float4*)&frS[2*1024 + wd*4];
        float acc;
        acc = fl0.x * a0.x;
        acc = fmaf(fl0.y, a0.y, acc);
        acc = fmaf(fl0.z, a0.z, acc);
        acc = fmaf(fl0.w, a0.w, acc);
        acc = fmaf(fl1.x, a1.x, acc);
        acc = fmaf(fl1.y, a1.y, acc);
        acc = fmaf(fl1.z, a1.z, acc);
        acc = fmaf(fl1.w, a1.w, acc);
        acc = fmaf(fl2.x, a2.x, acc);
        acc = fmaf(fl2.y, a2.y, acc);
        acc = fmaf(fl2.z, a2.z, acc);
        acc = fmaf(fl2.w, a2.w, acc);
        out[ob + (size_t)d * HW_] = fmaf(acc, A, psiS[d]);   // coalesced dword
    }
}

// ---------------------------------------------------------------------------
extern "C" void kernel_launch(void* const* d_in, const int* in_sizes, int n_in,
                              void* d_out, int out_size, void* d_ws, size_t ws_size,
                              hipStream_t stream) {
    const float* F_L = (const float*)d_in[0];
    const float* F_R = (const float*)d_in[1];
    const float* WL  = (const float*)d_in[2];
    const float* WR  = (const float*)d_in[3];
    float* out = (float*)d_out;
    float* ws  = (float*)d_ws;

    const size_t PROJ = (size_t)B_ * H_ * G_ * ROWF;   // 6,291,456 floats
    float* PLp = ws;
    float* PRp = ws + PROJ;
    float* WtL = ws + 2 * PROJ;
    float* WtR = WtL + CIN * CC;
    // ws bytes needed: (2*6291456 + 2*6144)*4 = ~48.05 MiB

    wtrans_kernel<<<(2 * CIN * CC + 255) / 256, 256, 0, stream>>>(WL, WR, WtL, WtR);
    proj_kernel<<<dim3(B_ * HW_ / 256, 2), 256, 0, stream>>>(F_L, F_R, WtL, WtR, PLp, PRp);
    sim_kernel<<<B_ * G_ * H_, 256, 0, stream>>>(PLp, PRp, out);
}